// Round 1
// baseline (303.002 us; speedup 1.0000x reference)
//
#include <hip/hip_runtime.h>
#include <hip/hip_bf16.h>

#define N_NODES 10000
#define N_EDGES 640000
#define CH 128

// ---------------------------------------------------------------------------
// Phase A: per-node edge count + weighted degree via global atomics.
// 640000 edges, one per thread. Atomics spread over 10000 addresses
// (~160 cache lines across L2 channels) — contention is negligible.
__global__ __launch_bounds__(256) void cnt_kernel(const int* __restrict__ ei,
                                                  const float* __restrict__ ew,
                                                  int* __restrict__ tot,
                                                  float* __restrict__ deg) {
    int e = blockIdx.x * 256 + threadIdx.x;      // grid = 2500 exactly covers E
    int c = ei[N_EDGES + e];
    float w = ew[e];
    atomicAdd(&tot[c], 1);
    atomicAdd(&deg[c], w);
}

// ---------------------------------------------------------------------------
// Phase B: single-block scan. tot -> exclusive prefix offs (and cursor copy),
// dinv = rsqrt(deg+1), plus conv+fc weight folding (vbuf, c0).
__global__ __launch_bounds__(1024) void scan_kernel(const int* __restrict__ tot,
        const float* __restrict__ deg, int* __restrict__ offs, int* __restrict__ cur,
        float* __restrict__ dinv,
        const float* __restrict__ conv_w, const float* __restrict__ conv_b,
        const float* __restrict__ fc_w, const float* __restrict__ fc_b,
        float* __restrict__ vbuf, float* __restrict__ c0) {
    __shared__ int lt[10240];                    // 40 KB staged counts
    __shared__ int wsum[16];
    int t = threadIdx.x;
    for (int i = t; i < 10240; i += 1024) lt[i] = (i < N_NODES) ? tot[i] : 0;
    // independent work while counts land in LDS:
    for (int i = t; i < N_NODES; i += 1024) dinv[i] = rsqrtf(deg[i] + 1.0f);
    if (t < 384) {                               // fold fc into conv weights
        float s = 0.0f;
        for (int o = 0; o < CH; ++o) s += fc_w[o] * conv_w[o * 384 + t];
        vbuf[t] = s;
    } else if (t == 384) {
        float s = fc_b[0];
        for (int o = 0; o < CH; ++o) s += fc_w[o] * conv_b[o];
        *c0 = s;
    }
    __syncthreads();
    // 10 elements per thread
    int base = t * 10;
    int loc[10]; int s = 0;
    #pragma unroll
    for (int j = 0; j < 10; ++j) { loc[j] = s; s += lt[base + j]; }
    int lane = t & 63, wave = t >> 6;
    int inc = s;                                 // inclusive wave scan
    #pragma unroll
    for (int off = 1; off < 64; off <<= 1) {
        int u = __shfl_up(inc, off, 64);
        if (lane >= off) inc += u;
    }
    if (lane == 63) wsum[wave] = inc;
    __syncthreads();
    int wbase = 0;
    for (int i = 0; i < wave; ++i) wbase += wsum[i];
    int ex = wbase + inc - s;                    // exclusive prefix of this thread
    #pragma unroll
    for (int j = 0; j < 10; ++j) lt[base + j] = ex + loc[j];
    __syncthreads();
    for (int i = t; i < N_NODES; i += 1024) {
        int v = lt[i];
        offs[i] = v;
        cur[i] = v;
    }
}

// ---------------------------------------------------------------------------
// Phase C: scatter edges into CSR order via global cursor atomics.
// Packed {src, norm-val} 8B records. No LDS -> full occupancy, single pass.
__global__ __launch_bounds__(256) void scatter_kernel(const int* __restrict__ ei,
        const float* __restrict__ ew, const float* __restrict__ dinv,
        int* __restrict__ cur, int2* __restrict__ erec) {
    int e = blockIdx.x * 256 + threadIdx.x;      // grid = 2500
    int r = ei[e];
    int c = ei[N_EDGES + e];
    float v = dinv[r] * ew[e] * dinv[c];
    int p = atomicAdd(&cur[c], 1);
    erec[p] = make_int2(r, __float_as_int(v));
}

// ---------------------------------------------------------------------------
// GEMM: out[m][o] = sum_k A[m][k] * W[o][k];  A:[M][128], W:[128][128] row-major.
__global__ __launch_bounds__(256) void gemm128_kernel(const float* __restrict__ A,
                                                      const float* __restrict__ W,
                                                      float* __restrict__ out, int M) {
    __shared__ float As[32][68];
    __shared__ float Ws[32][132];
    int tid = threadIdx.x;
    int tx = tid & 31;
    int ty = tid >> 5;
    int row0 = blockIdx.x * 64;
    float acc[8][4] = {};
    for (int k0 = 0; k0 < 128; k0 += 32) {
        #pragma unroll
        for (int i = 0; i < 8; ++i) {
            int idx = tid + i * 256;
            int r = idx >> 5, k = idx & 31;
            int gr = row0 + r;
            As[k][r] = (gr < M) ? A[gr * CH + k0 + k] : 0.0f;
        }
        #pragma unroll
        for (int i = 0; i < 16; ++i) {
            int idx = tid + i * 256;
            int o = idx >> 5, k = idx & 31;
            Ws[k][o] = W[o * CH + k0 + k];
        }
        __syncthreads();
        #pragma unroll
        for (int kk = 0; kk < 32; ++kk) {
            float a[8], w[4];
            #pragma unroll
            for (int j = 0; j < 8; ++j) a[j] = As[kk][ty * 8 + j];
            #pragma unroll
            for (int c = 0; c < 4; ++c) w[c] = Ws[kk][tx * 4 + c];
            #pragma unroll
            for (int j = 0; j < 8; ++j)
                #pragma unroll
                for (int c = 0; c < 4; ++c)
                    acc[j][c] += a[j] * w[c];
        }
        __syncthreads();
    }
    #pragma unroll
    for (int j = 0; j < 8; ++j) {
        int gr = row0 + ty * 8 + j;
        if (gr < M) {
            float4 v = make_float4(acc[j][0], acc[j][1], acc[j][2], acc[j][3]);
            *reinterpret_cast<float4*>(&out[gr * CH + tx * 4]) = v;
        }
    }
}

// ---------------------------------------------------------------------------
// Aggregation: 32 lanes per node (float4/lane), 8 nodes/block, unroll x8.
__global__ __launch_bounds__(256) void agg_kernel(const float4* __restrict__ xw4,
        const int2* __restrict__ erec, const int* __restrict__ offs,
        const int* __restrict__ cnt, const float* __restrict__ dinv,
        const float4* __restrict__ bias4, float4* __restrict__ out4) {
    int l = threadIdx.x & 31;                  // channel quad
    int g = threadIdx.x >> 5;                  // node group 0..7
    int n = blockIdx.x * 8 + g;
    float d = dinv[n];
    float dd = d * d;
    float4 self = xw4[n * 32 + l];
    float4 acc = make_float4(dd * self.x, dd * self.y, dd * self.z, dd * self.w);
    int start = offs[n];
    int num = cnt[n];
    int i = 0;
    for (; i + 8 <= num; i += 8) {
        int2 r[8];
        #pragma unroll
        for (int j = 0; j < 8; ++j) r[j] = erec[start + i + j];
        float4 f[8];
        #pragma unroll
        for (int j = 0; j < 8; ++j) f[j] = xw4[r[j].x * 32 + l];
        #pragma unroll
        for (int j = 0; j < 8; ++j) {
            float v = __int_as_float(r[j].y);
            acc.x += v * f[j].x; acc.y += v * f[j].y;
            acc.z += v * f[j].z; acc.w += v * f[j].w;
        }
    }
    for (; i < num; ++i) {
        int2 r = erec[start + i];
        float4 f = xw4[r.x * 32 + l];
        float v = __int_as_float(r.y);
        acc.x += v * f.x; acc.y += v * f.y; acc.z += v * f.z; acc.w += v * f.w;
    }
    float4 bb = bias4[l];
    acc.x = fmaxf(acc.x + bb.x, 0.0f);
    acc.y = fmaxf(acc.y + bb.y, 0.0f);
    acc.z = fmaxf(acc.z + bb.z, 0.0f);
    acc.w = fmaxf(acc.w + bb.w, 0.0f);
    out4[n * 32 + l] = acc;
}

// ---------------------------------------------------------------------------
// Fused temporal conv + fc: one wave per node, lane handles ch l and l+64.
__global__ __launch_bounds__(256) void convfc_kernel(const float* __restrict__ h,
        const float* __restrict__ v, const float* __restrict__ c0,
        float* __restrict__ out, int N) {
    int n = blockIdx.x * 4 + (threadIdx.x >> 6);
    int l = threadIdx.x & 63;
    if (n >= N) return;
    const float* hn = h + n * CH;
    float v0a = v[l * 3 + 0],        v1a = v[l * 3 + 1],        v2a = v[l * 3 + 2];
    float v0b = v[(l + 64) * 3 + 0], v1b = v[(l + 64) * 3 + 1], v2b = v[(l + 64) * 3 + 2];
    float p = hn[l] * v1a + hn[l + 64] * v1b;
    if (n > 0)     p += hn[l - CH] * v0a + hn[l + 64 - CH] * v0b;
    if (n < N - 1) p += hn[l + CH] * v2a + hn[l + 64 + CH] * v2b;
    #pragma unroll
    for (int off = 32; off > 0; off >>= 1) p += __shfl_down(p, off, 64);
    if (l == 0) out[n] = p + *c0;
}

// ---------------------------------------------------------------------------
extern "C" void kernel_launch(void* const* d_in, const int* in_sizes, int n_in,
                              void* d_out, int out_size, void* d_ws, size_t ws_size,
                              hipStream_t stream) {
    const float* x       = (const float*)d_in[0];
    const int*   ei      = (const int*)d_in[1];
    const float* ew      = (const float*)d_in[2];
    const float* W1      = (const float*)d_in[3];
    const float* b1      = (const float*)d_in[4];
    const float* W2      = (const float*)d_in[5];
    const float* b2      = (const float*)d_in[6];
    const float* conv_w  = (const float*)d_in[7];
    const float* conv_b  = (const float*)d_in[8];
    const float* fc_w    = (const float*)d_in[9];
    const float* fc_b    = (const float*)d_in[10];
    float* out = (float*)d_out;

    // Workspace layout (no aliasing needed anymore): ~14.9 MB total
    float* bufA   = (float*)d_ws;                   // 1,280,000 f
    float* bufB   = bufA + N_NODES * CH;            // 1,280,000 f
    int2*  erec   = (int2*)(bufB + N_NODES * CH);   // 640,000 x 8B
    int*   tot    = (int*)(erec + N_EDGES);         // 10,000 i   (zeroed)
    float* deg    = (float*)(tot + N_NODES);        // 10,000 f   (zeroed, contiguous with tot)
    int*   offs   = (int*)(deg + N_NODES);          // 10,000 i
    int*   cur    = offs + N_NODES;                 // 10,000 i
    float* dinv   = (float*)(cur + N_NODES);        // 10,000 f
    float* vbuf   = dinv + N_NODES;                 // 384 f
    float* c0     = vbuf + 384;                     // 1 f

    // --- CSR build via global atomics (replaces hist/reduce/bofs/scatter) ---
    hipMemsetAsync(tot, 0, 2 * N_NODES * sizeof(int), stream);
    cnt_kernel<<<N_EDGES / 256, 256, 0, stream>>>(ei, ew, tot, deg);
    scan_kernel<<<1, 1024, 0, stream>>>(tot, deg, offs, cur, dinv,
                                        conv_w, conv_b, fc_w, fc_b, vbuf, c0);
    scatter_kernel<<<N_EDGES / 256, 256, 0, stream>>>(ei, ew, dinv, cur, erec);

    const int gemm_grid = (N_NODES + 63) / 64;
    // --- layer 1 ---
    gemm128_kernel<<<gemm_grid, 256, 0, stream>>>(x, W1, bufA, N_NODES);
    agg_kernel<<<N_NODES / 8, 256, 0, stream>>>((const float4*)bufA, erec, offs, tot,
                                                dinv, (const float4*)b1, (float4*)bufB);
    // --- layer 2 ---
    gemm128_kernel<<<gemm_grid, 256, 0, stream>>>(bufB, W2, bufA, N_NODES);
    agg_kernel<<<N_NODES / 8, 256, 0, stream>>>((const float4*)bufA, erec, offs, tot,
                                                dinv, (const float4*)b2, (float4*)bufB);
    // --- fused temporal conv + fc ---
    convfc_kernel<<<(N_NODES + 3) / 4, 256, 0, stream>>>(bufB, vbuf, c0, out, N_NODES);
}

// Round 2
// 225.536 us; speedup vs baseline: 1.3435x; 1.3435x over previous
//
#include <hip/hip_runtime.h>
#include <hip/hip_bf16.h>

#define N_NODES 10000
#define N_EDGES 640000
#define CH 128
#define NB 256               // histogram/scatter blocks
#define EPB (N_EDGES / NB)   // 2500 edges per block
#define NCHUNK 40            // ceil(N_NODES/256) scan chunks

// ---------------------------------------------------------------------------
// K1: FUSED. Blocks [0,NB): per-block LDS count histogram (40 KB, no global
// atomics). Blocks [NB, NB+157): gemm1 = x @ W1^T (independent of the graph).
// Shared LDS is a 40 KB union of the two paths.
__global__ __launch_bounds__(256) void fused_hist_gemm(const int* __restrict__ ei,
        const float* __restrict__ x, const float* __restrict__ W1,
        int* __restrict__ hist, float* __restrict__ out) {
    __shared__ __align__(16) char smem[40000];
    int t = threadIdx.x;
    if (blockIdx.x < NB) {
        int* h = (int*)smem;
        int b = blockIdx.x;
        for (int i = t; i < N_NODES; i += 256) h[i] = 0;
        __syncthreads();
        int e0 = b * EPB;
        for (int i = t; i < EPB; i += 256)
            atomicAdd(&h[ei[N_EDGES + e0 + i]], 1);      // LDS atomic
        __syncthreads();
        for (int i = t; i < N_NODES; i += 256)
            hist[b * N_NODES + i] = h[i];
        return;
    }
    // ---- gemm path: out[m][o] = sum_k x[m][k] * W1[o][k] ----
    float (*As)[68]  = (float(*)[68])smem;               //  8704 B
    float (*Ws)[132] = (float(*)[132])(smem + 32 * 68 * sizeof(float)); // 16896 B
    int tx = t & 31;
    int ty = t >> 5;
    int row0 = (blockIdx.x - NB) * 64;
    float acc[8][4] = {};
    for (int k0 = 0; k0 < 128; k0 += 32) {
        #pragma unroll
        for (int i = 0; i < 8; ++i) {
            int idx = t + i * 256;
            int r = idx >> 5, k = idx & 31;
            int gr = row0 + r;
            As[k][r] = (gr < N_NODES) ? x[gr * CH + k0 + k] : 0.0f;
        }
        #pragma unroll
        for (int i = 0; i < 16; ++i) {
            int idx = t + i * 256;
            int o = idx >> 5, k = idx & 31;
            Ws[k][o] = W1[o * CH + k0 + k];
        }
        __syncthreads();
        #pragma unroll
        for (int kk = 0; kk < 32; ++kk) {
            float a[8], w[4];
            #pragma unroll
            for (int j = 0; j < 8; ++j) a[j] = As[kk][ty * 8 + j];
            #pragma unroll
            for (int c = 0; c < 4; ++c) w[c] = Ws[kk][tx * 4 + c];
            #pragma unroll
            for (int j = 0; j < 8; ++j)
                #pragma unroll
                for (int c = 0; c < 4; ++c)
                    acc[j][c] += a[j] * w[c];
        }
        __syncthreads();
    }
    #pragma unroll
    for (int j = 0; j < 8; ++j) {
        int gr = row0 + ty * 8 + j;
        if (gr < N_NODES) {
            float4 v = make_float4(acc[j][0], acc[j][1], acc[j][2], acc[j][3]);
            *reinterpret_cast<float4*>(&out[gr * CH + tx * 4]) = v;
        }
    }
}

// ---------------------------------------------------------------------------
// K2: reduce histograms -> tot, per-chunk sums csum[40].
// Extra block (blockIdx == NCHUNK) folds fc into conv weights (vbuf, c0).
__global__ __launch_bounds__(256) void reduce_kernel(const int* __restrict__ hist,
        int* __restrict__ tot, int* __restrict__ csum,
        const float* __restrict__ conv_w, const float* __restrict__ conv_b,
        const float* __restrict__ fc_w, const float* __restrict__ fc_b,
        float* __restrict__ vbuf, float* __restrict__ c0) {
    int blk = blockIdx.x, t = threadIdx.x;
    if (blk == NCHUNK) {
        for (int i = t; i <= 384; i += 256) {
            if (i < 384) {
                float s = 0.0f;
                for (int o = 0; o < CH; ++o) s += fc_w[o] * conv_w[o * 384 + i];
                vbuf[i] = s;
            } else {
                float s = fc_b[0];
                for (int o = 0; o < CH; ++o) s += fc_w[o] * conv_b[o];
                *c0 = s;
            }
        }
        return;
    }
    int n = blk * 256 + t;
    int c = 0;
    if (n < N_NODES) {
        #pragma unroll 8
        for (int b = 0; b < NB; ++b) c += hist[b * N_NODES + n];
        tot[n] = c;
    }
    __shared__ int wred[4];
    int lane = t & 63, wave = t >> 6;
    int s = c;
    #pragma unroll
    for (int off = 32; off > 0; off >>= 1) s += __shfl_down(s, off, 64);
    if (lane == 0) wred[wave] = s;
    __syncthreads();
    if (t == 0) csum[blk] = wred[0] + wred[1] + wred[2] + wred[3];
}

// ---------------------------------------------------------------------------
// K3: offs[n] = global exclusive prefix of tot; convert hist columns to
// per-(block,node) start cursors in place.
__global__ __launch_bounds__(256) void bofs_kernel(int* __restrict__ hist,
        const int* __restrict__ tot, const int* __restrict__ csum,
        int* __restrict__ offs) {
    __shared__ int lds_csum[NCHUNK];
    __shared__ int wsum[4];
    int blk = blockIdx.x, t = threadIdx.x;
    if (t < NCHUNK) lds_csum[t] = csum[t];
    __syncthreads();
    int base = 0;
    for (int i = 0; i < blk; ++i) base += lds_csum[i];
    int n = blk * 256 + t;
    int v = (n < N_NODES) ? tot[n] : 0;
    int lane = t & 63, wave = t >> 6;
    int s = v;
    #pragma unroll
    for (int off = 1; off < 64; off <<= 1) {
        int u = __shfl_up(s, off, 64);
        if (lane >= off) s += u;
    }
    if (lane == 63) wsum[wave] = s;
    __syncthreads();
    int wbase = 0;
    for (int i = 0; i < wave; ++i) wbase += wsum[i];
    if (n < N_NODES) {
        int run = base + wbase + s - v;          // global exclusive prefix
        offs[n] = run;
        for (int b = 0; b < NB; ++b) {
            int h = hist[b * N_NODES + n];
            hist[b * N_NODES + n] = run;
            run += h;
        }
    }
}

// ---------------------------------------------------------------------------
// K4: scatter edges into CSR order via LDS cursors. Records hold {src, RAW w}
// — normalization is applied later (deg isn't known yet).
__global__ __launch_bounds__(256) void scatter_kernel(const int* __restrict__ ei,
        const float* __restrict__ ew, const int* __restrict__ bofs,
        int2* __restrict__ erec) {
    __shared__ int cur[N_NODES];                 // 40 KB
    int b = blockIdx.x, t = threadIdx.x;
    for (int i = t; i < N_NODES; i += 256) cur[i] = bofs[b * N_NODES + i];
    __syncthreads();
    int e0 = b * EPB;
    for (int i = t; i < EPB; i += 256) {
        int e = e0 + i;
        int r = ei[e];
        int c = ei[N_EDGES + e];
        int p = atomicAdd(&cur[c], 1);           // LDS atomic
        erec[p] = make_int2(r, __float_as_int(ew[e]));
    }
}

// ---------------------------------------------------------------------------
// K5: weighted degree from CSR segments (coalesced) -> dinv = rsqrt(deg+1).
// 8 nodes/block, 32 lanes per node.
__global__ __launch_bounds__(256) void deg_kernel(const int2* __restrict__ erec,
        const int* __restrict__ offs, const int* __restrict__ cnt,
        float* __restrict__ dinv) {
    int n = blockIdx.x * 8 + (threadIdx.x >> 5);
    int l = threadIdx.x & 31;
    int start = offs[n];
    int num = cnt[n];
    float s = 0.0f;
    for (int i = l; i < num; i += 32) s += __int_as_float(erec[start + i].y);
    #pragma unroll
    for (int off = 16; off > 0; off >>= 1) s += __shfl_down(s, off, 32);
    if (l == 0) dinv[n] = rsqrtf(s + 1.0f);      // +1 = self-loop weight
}

// ---------------------------------------------------------------------------
// GEMM (standalone, layer 2): out[m][o] = sum_k A[m][k] * W[o][k].
__global__ __launch_bounds__(256) void gemm128_kernel(const float* __restrict__ A,
                                                      const float* __restrict__ W,
                                                      float* __restrict__ out, int M) {
    __shared__ float As[32][68];
    __shared__ float Ws[32][132];
    int tid = threadIdx.x;
    int tx = tid & 31;
    int ty = tid >> 5;
    int row0 = blockIdx.x * 64;
    float acc[8][4] = {};
    for (int k0 = 0; k0 < 128; k0 += 32) {
        #pragma unroll
        for (int i = 0; i < 8; ++i) {
            int idx = tid + i * 256;
            int r = idx >> 5, k = idx & 31;
            int gr = row0 + r;
            As[k][r] = (gr < M) ? A[gr * CH + k0 + k] : 0.0f;
        }
        #pragma unroll
        for (int i = 0; i < 16; ++i) {
            int idx = tid + i * 256;
            int o = idx >> 5, k = idx & 31;
            Ws[k][o] = W[o * CH + k0 + k];
        }
        __syncthreads();
        #pragma unroll
        for (int kk = 0; kk < 32; ++kk) {
            float a[8], w[4];
            #pragma unroll
            for (int j = 0; j < 8; ++j) a[j] = As[kk][ty * 8 + j];
            #pragma unroll
            for (int c = 0; c < 4; ++c) w[c] = Ws[kk][tx * 4 + c];
            #pragma unroll
            for (int j = 0; j < 8; ++j)
                #pragma unroll
                for (int c = 0; c < 4; ++c)
                    acc[j][c] += a[j] * w[c];
        }
        __syncthreads();
    }
    #pragma unroll
    for (int j = 0; j < 8; ++j) {
        int gr = row0 + ty * 8 + j;
        if (gr < M) {
            float4 v = make_float4(acc[j][0], acc[j][1], acc[j][2], acc[j][3]);
            *reinterpret_cast<float4*>(&out[gr * CH + tx * 4]) = v;
        }
    }
}

// ---------------------------------------------------------------------------
// Aggregation with dinv folded in: out[n] = relu(d_n*(sum_e w_e*d_{r_e}*xw[r_e]
//                                                     + d_n*xw[n]) + b)
// Records carry raw w; dinv[r] is an L2-resident 4B broadcast load per edge.
__global__ __launch_bounds__(256) void agg_kernel(const float4* __restrict__ xw4,
        const int2* __restrict__ erec, const int* __restrict__ offs,
        const int* __restrict__ cnt, const float* __restrict__ dinv,
        const float4* __restrict__ bias4, float4* __restrict__ out4) {
    int l = threadIdx.x & 31;                  // channel quad
    int g = threadIdx.x >> 5;                  // node group 0..7
    int n = blockIdx.x * 8 + g;
    float d = dinv[n];
    float4 self = xw4[n * 32 + l];
    float4 acc = make_float4(d * self.x, d * self.y, d * self.z, d * self.w);
    int start = offs[n];
    int num = cnt[n];
    int i = 0;
    for (; i + 8 <= num; i += 8) {
        int2 r[8];
        #pragma unroll
        for (int j = 0; j < 8; ++j) r[j] = erec[start + i + j];
        float4 f[8];
        float dr[8];
        #pragma unroll
        for (int j = 0; j < 8; ++j) f[j] = xw4[r[j].x * 32 + l];
        #pragma unroll
        for (int j = 0; j < 8; ++j) dr[j] = dinv[r[j].x];
        #pragma unroll
        for (int j = 0; j < 8; ++j) {
            float v = __int_as_float(r[j].y) * dr[j];
            acc.x += v * f[j].x; acc.y += v * f[j].y;
            acc.z += v * f[j].z; acc.w += v * f[j].w;
        }
    }
    for (; i < num; ++i) {
        int2 r = erec[start + i];
        float4 f = xw4[r.x * 32 + l];
        float v = __int_as_float(r.y) * dinv[r.x];
        acc.x += v * f.x; acc.y += v * f.y; acc.z += v * f.z; acc.w += v * f.w;
    }
    float4 bb = bias4[l];
    acc.x = fmaxf(d * acc.x + bb.x, 0.0f);
    acc.y = fmaxf(d * acc.y + bb.y, 0.0f);
    acc.z = fmaxf(d * acc.z + bb.z, 0.0f);
    acc.w = fmaxf(d * acc.w + bb.w, 0.0f);
    out4[n * 32 + l] = acc;
}

// ---------------------------------------------------------------------------
// Fused temporal conv + fc: one wave per node, lane handles ch l and l+64.
__global__ __launch_bounds__(256) void convfc_kernel(const float* __restrict__ h,
        const float* __restrict__ v, const float* __restrict__ c0,
        float* __restrict__ out, int N) {
    int n = blockIdx.x * 4 + (threadIdx.x >> 6);
    int l = threadIdx.x & 63;
    if (n >= N) return;
    const float* hn = h + n * CH;
    float v0a = v[l * 3 + 0],        v1a = v[l * 3 + 1],        v2a = v[l * 3 + 2];
    float v0b = v[(l + 64) * 3 + 0], v1b = v[(l + 64) * 3 + 1], v2b = v[(l + 64) * 3 + 2];
    float p = hn[l] * v1a + hn[l + 64] * v1b;
    if (n > 0)     p += hn[l - CH] * v0a + hn[l + 64 - CH] * v0b;
    if (n < N - 1) p += hn[l + CH] * v2a + hn[l + 64 + CH] * v2b;
    #pragma unroll
    for (int off = 32; off > 0; off >>= 1) p += __shfl_down(p, off, 64);
    if (l == 0) out[n] = p + *c0;
}

// ---------------------------------------------------------------------------
extern "C" void kernel_launch(void* const* d_in, const int* in_sizes, int n_in,
                              void* d_out, int out_size, void* d_ws, size_t ws_size,
                              hipStream_t stream) {
    const float* x       = (const float*)d_in[0];
    const int*   ei      = (const int*)d_in[1];
    const float* ew      = (const float*)d_in[2];
    const float* W1      = (const float*)d_in[3];
    const float* b1      = (const float*)d_in[4];
    const float* W2      = (const float*)d_in[5];
    const float* b2      = (const float*)d_in[6];
    const float* conv_w  = (const float*)d_in[7];
    const float* conv_b  = (const float*)d_in[8];
    const float* fc_w    = (const float*)d_in[9];
    const float* fc_b    = (const float*)d_in[10];
    float* out = (float*)d_out;

    float* bufA   = (float*)d_ws;                   // 1,280,000 f
    float* bufB   = bufA + N_NODES * CH;            // 1,280,000 f
    int2*  erec   = (int2*)(bufB + N_NODES * CH);   // 640,000 x 8B
    int*   hist   = (int*)(erec + N_EDGES);         // NB*10,000 i
    int*   tot    = hist + NB * N_NODES;            // 10,000 i
    int*   offs   = tot + N_NODES;                  // 10,000 i
    float* dinv   = (float*)(offs + N_NODES);       // 10,000 f
    float* vbuf   = dinv + N_NODES;                 // 384 f
    float* c0     = vbuf + 384;                     // 1 f
    int*   csum   = (int*)(c0 + 1);                 // NCHUNK i

    const int gemm_grid = (N_NODES + 63) / 64;      // 157

    // K1: histogram (256 blocks) + gemm1 (157 blocks) fused, data-independent
    fused_hist_gemm<<<NB + gemm_grid, 256, 0, stream>>>(ei, x, W1, hist, bufA);
    reduce_kernel<<<NCHUNK + 1, 256, 0, stream>>>(hist, tot, csum,
                                                  conv_w, conv_b, fc_w, fc_b, vbuf, c0);
    bofs_kernel<<<NCHUNK, 256, 0, stream>>>(hist, tot, csum, offs);
    scatter_kernel<<<NB, 256, 0, stream>>>(ei, ew, hist, erec);
    deg_kernel<<<N_NODES / 8, 256, 0, stream>>>(erec, offs, tot, dinv);

    // layer 1 aggregation (gemm1 output already in bufA)
    agg_kernel<<<N_NODES / 8, 256, 0, stream>>>((const float4*)bufA, erec, offs, tot,
                                                dinv, (const float4*)b1, (float4*)bufB);
    // layer 2
    gemm128_kernel<<<gemm_grid, 256, 0, stream>>>(bufB, W2, bufA, N_NODES);
    agg_kernel<<<N_NODES / 8, 256, 0, stream>>>((const float4*)bufA, erec, offs, tot,
                                                dinv, (const float4*)b2, (float4*)bufB);
    // fused temporal conv + fc
    convfc_kernel<<<(N_NODES + 3) / 4, 256, 0, stream>>>(bufB, vbuf, c0, out, N_NODES);
}

// Round 3
// 219.546 us; speedup vs baseline: 1.3801x; 1.0273x over previous
//
#include <hip/hip_runtime.h>
#include <hip/hip_bf16.h>

#define N_NODES 10000
#define N_EDGES 640000
#define CH 128
#define NB 64                // histogram/scatter blocks
#define EPB (N_EDGES / NB)   // 10000 edges per block
#define NCHUNK 40            // ceil(N_NODES/256) scan chunks
#define NPAD 10240           // NCHUNK*256

// ---------------------------------------------------------------------------
// K1: FUSED. Blocks [0,NB): per-block LDS count histogram + chunk partials.
// Blocks [NB, NB+157): gemm1 = x @ W1^T. Block NB+157: conv/fc weight fold.
__global__ __launch_bounds__(256) void fused_hist_gemm(const int* __restrict__ ei,
        const float* __restrict__ x, const float* __restrict__ W1,
        int* __restrict__ hist, int* __restrict__ pcs, float* __restrict__ out,
        const float* __restrict__ conv_w, const float* __restrict__ conv_b,
        const float* __restrict__ fc_w, const float* __restrict__ fc_b,
        float* __restrict__ vbuf, float* __restrict__ c0) {
    __shared__ __align__(16) char smem[NPAD * 4];    // 40960 B union
    int t = threadIdx.x;
    int bid = blockIdx.x;
    if (bid < NB) {
        // ---- histogram path ----
        int* h = (int*)smem;
        for (int i = t; i < NPAD; i += 256) h[i] = 0;
        __syncthreads();
        int e0 = bid * EPB;
        for (int i = t; i < EPB; i += 256)
            atomicAdd(&h[ei[N_EDGES + e0 + i]], 1);  // LDS atomic
        __syncthreads();
        for (int i = t; i < N_NODES; i += 256)
            hist[bid * N_NODES + i] = h[i];
        // chunk partial sums: wave w handles chunks w, w+4, ...
        int lane = t & 63, wave = t >> 6;
        for (int cch = wave; cch < NCHUNK; cch += 4) {
            int s = h[cch * 256 + lane] + h[cch * 256 + lane + 64]
                  + h[cch * 256 + lane + 128] + h[cch * 256 + lane + 192];
            #pragma unroll
            for (int off = 32; off > 0; off >>= 1) s += __shfl_down(s, off, 64);
            if (lane == 0) pcs[cch * NB + bid] = s;  // chunk-major layout
        }
        return;
    }
    if (bid == NB + (N_NODES + 63) / 64) {
        // ---- conv/fc weight folding ----
        for (int i = t; i <= 384; i += 256) {
            if (i < 384) {
                float s = 0.0f;
                for (int o = 0; o < CH; ++o) s += fc_w[o] * conv_w[o * 384 + i];
                vbuf[i] = s;
            } else {
                float s = fc_b[0];
                for (int o = 0; o < CH; ++o) s += fc_w[o] * conv_b[o];
                *c0 = s;
            }
        }
        return;
    }
    // ---- gemm path: out[m][o] = sum_k x[m][k] * W1[o][k] ----
    float (*As)[68]  = (float(*)[68])smem;
    float (*Ws)[132] = (float(*)[132])(smem + 32 * 68 * sizeof(float));
    int tx = t & 31;
    int ty = t >> 5;
    int row0 = (bid - NB) * 64;
    float acc[8][4] = {};
    for (int k0 = 0; k0 < 128; k0 += 32) {
        #pragma unroll
        for (int i = 0; i < 8; ++i) {
            int idx = t + i * 256;
            int r = idx >> 5, k = idx & 31;
            int gr = row0 + r;
            As[k][r] = (gr < N_NODES) ? x[gr * CH + k0 + k] : 0.0f;
        }
        #pragma unroll
        for (int i = 0; i < 16; ++i) {
            int idx = t + i * 256;
            int o = idx >> 5, k = idx & 31;
            Ws[k][o] = W1[o * CH + k0 + k];
        }
        __syncthreads();
        #pragma unroll
        for (int kk = 0; kk < 32; ++kk) {
            float a[8], w[4];
            #pragma unroll
            for (int j = 0; j < 8; ++j) a[j] = As[kk][ty * 8 + j];
            #pragma unroll
            for (int c = 0; c < 4; ++c) w[c] = Ws[kk][tx * 4 + c];
            #pragma unroll
            for (int j = 0; j < 8; ++j)
                #pragma unroll
                for (int c = 0; c < 4; ++c)
                    acc[j][c] += a[j] * w[c];
        }
        __syncthreads();
    }
    #pragma unroll
    for (int j = 0; j < 8; ++j) {
        int gr = row0 + ty * 8 + j;
        if (gr < N_NODES) {
            float4 v = make_float4(acc[j][0], acc[j][1], acc[j][2], acc[j][3]);
            *reinterpret_cast<float4*>(&out[gr * CH + tx * 4]) = v;
        }
    }
}

// ---------------------------------------------------------------------------
// K2: per-node totals + global exclusive prefix + cursor conversion, all in
// one kernel. Chunk base comes from pcs (chunk-major: first blk*NB ints).
__global__ __launch_bounds__(256) void bofs_kernel(int* __restrict__ hist,
        const int* __restrict__ pcs, int* __restrict__ tot,
        int* __restrict__ offs) {
    __shared__ int wred[4];
    __shared__ int wsum[4];
    __shared__ int base_sh;
    int blk = blockIdx.x, t = threadIdx.x;
    int lane = t & 63, wave = t >> 6;
    // --- base = edges into nodes of earlier chunks ---
    int bsum = 0;
    for (int i = t; i < blk * NB; i += 256) bsum += pcs[i];
    #pragma unroll
    for (int off = 32; off > 0; off >>= 1) bsum += __shfl_down(bsum, off, 64);
    if (lane == 0) wred[wave] = bsum;
    __syncthreads();
    if (t == 0) base_sh = wred[0] + wred[1] + wred[2] + wred[3];
    // --- per-node total over 64 hist rows ---
    int n = blk * 256 + t;
    int v = 0;
    if (n < N_NODES) {
        #pragma unroll 8
        for (int b = 0; b < NB; ++b) v += hist[b * N_NODES + n];
        tot[n] = v;
    }
    // --- 256-wide scan (wave scan + wave offsets) ---
    int s = v;
    #pragma unroll
    for (int off = 1; off < 64; off <<= 1) {
        int u = __shfl_up(s, off, 64);
        if (lane >= off) s += u;
    }
    if (lane == 63) wsum[wave] = s;
    __syncthreads();
    int wbase = 0;
    for (int i = 0; i < wave; ++i) wbase += wsum[i];
    if (n < N_NODES) {
        int run = base_sh + wbase + s - v;        // global exclusive prefix
        offs[n] = run;
        for (int b = 0; b < NB; ++b) {
            int h = hist[b * N_NODES + n];
            hist[b * N_NODES + n] = run;          // column -> start cursor
            run += h;
        }
    }
}

// ---------------------------------------------------------------------------
// K3: scatter edges into CSR order via LDS cursors. Records hold {src, raw w}.
__global__ __launch_bounds__(256) void scatter_kernel(const int* __restrict__ ei,
        const float* __restrict__ ew, const int* __restrict__ bofs,
        int2* __restrict__ erec) {
    __shared__ int cur[N_NODES];                 // 40 KB
    int b = blockIdx.x, t = threadIdx.x;
    for (int i = t; i < N_NODES; i += 256) cur[i] = bofs[b * N_NODES + i];
    __syncthreads();
    int e0 = b * EPB;
    for (int i = t; i < EPB; i += 256) {
        int e = e0 + i;
        int r = ei[e];
        int c = ei[N_EDGES + e];
        int p = atomicAdd(&cur[c], 1);           // LDS atomic
        erec[p] = make_int2(r, __float_as_int(ew[e]));
    }
}

// ---------------------------------------------------------------------------
// K4: weighted degree from CSR segments (coalesced) -> dinv = rsqrt(deg+1).
__global__ __launch_bounds__(256) void deg_kernel(const int2* __restrict__ erec,
        const int* __restrict__ offs, const int* __restrict__ cnt,
        float* __restrict__ dinv) {
    int n = blockIdx.x * 8 + (threadIdx.x >> 5);
    int l = threadIdx.x & 31;
    int start = offs[n];
    int num = cnt[n];
    float s = 0.0f;
    for (int i = l; i < num; i += 32) s += __int_as_float(erec[start + i].y);
    #pragma unroll
    for (int off = 16; off > 0; off >>= 1) s += __shfl_down(s, off, 32);
    if (l == 0) dinv[n] = rsqrtf(s + 1.0f);      // +1 = self-loop weight
}

// ---------------------------------------------------------------------------
// GEMM (standalone, layer 2): out[m][o] = sum_k A[m][k] * W[o][k].
__global__ __launch_bounds__(256) void gemm128_kernel(const float* __restrict__ A,
                                                      const float* __restrict__ W,
                                                      float* __restrict__ out, int M) {
    __shared__ float As[32][68];
    __shared__ float Ws[32][132];
    int tid = threadIdx.x;
    int tx = tid & 31;
    int ty = tid >> 5;
    int row0 = blockIdx.x * 64;
    float acc[8][4] = {};
    for (int k0 = 0; k0 < 128; k0 += 32) {
        #pragma unroll
        for (int i = 0; i < 8; ++i) {
            int idx = tid + i * 256;
            int r = idx >> 5, k = idx & 31;
            int gr = row0 + r;
            As[k][r] = (gr < M) ? A[gr * CH + k0 + k] : 0.0f;
        }
        #pragma unroll
        for (int i = 0; i < 16; ++i) {
            int idx = tid + i * 256;
            int o = idx >> 5, k = idx & 31;
            Ws[k][o] = W[o * CH + k0 + k];
        }
        __syncthreads();
        #pragma unroll
        for (int kk = 0; kk < 32; ++kk) {
            float a[8], w[4];
            #pragma unroll
            for (int j = 0; j < 8; ++j) a[j] = As[kk][ty * 8 + j];
            #pragma unroll
            for (int c = 0; c < 4; ++c) w[c] = Ws[kk][tx * 4 + c];
            #pragma unroll
            for (int j = 0; j < 8; ++j)
                #pragma unroll
                for (int c = 0; c < 4; ++c)
                    acc[j][c] += a[j] * w[c];
        }
        __syncthreads();
    }
    #pragma unroll
    for (int j = 0; j < 8; ++j) {
        int gr = row0 + ty * 8 + j;
        if (gr < M) {
            float4 v = make_float4(acc[j][0], acc[j][1], acc[j][2], acc[j][3]);
            *reinterpret_cast<float4*>(&out[gr * CH + tx * 4]) = v;
        }
    }
}

// ---------------------------------------------------------------------------
// Aggregation: out[n] = relu(d_n*(sum_e w_e*d_{r_e}*xw[r_e]) + d_n^2*xw[n] + b)
__global__ __launch_bounds__(256) void agg_kernel(const float4* __restrict__ xw4,
        const int2* __restrict__ erec, const int* __restrict__ offs,
        const int* __restrict__ cnt, const float* __restrict__ dinv,
        const float4* __restrict__ bias4, float4* __restrict__ out4) {
    int l = threadIdx.x & 31;                  // channel quad
    int g = threadIdx.x >> 5;                  // node group 0..7
    int n = blockIdx.x * 8 + g;
    float d = dinv[n];
    float4 self = xw4[n * 32 + l];
    float4 acc = make_float4(d * self.x, d * self.y, d * self.z, d * self.w);
    int start = offs[n];
    int num = cnt[n];
    int i = 0;
    for (; i + 8 <= num; i += 8) {
        int2 r[8];
        #pragma unroll
        for (int j = 0; j < 8; ++j) r[j] = erec[start + i + j];
        float4 f[8];
        float dr[8];
        #pragma unroll
        for (int j = 0; j < 8; ++j) f[j] = xw4[r[j].x * 32 + l];
        #pragma unroll
        for (int j = 0; j < 8; ++j) dr[j] = dinv[r[j].x];
        #pragma unroll
        for (int j = 0; j < 8; ++j) {
            float v = __int_as_float(r[j].y) * dr[j];
            acc.x += v * f[j].x; acc.y += v * f[j].y;
            acc.z += v * f[j].z; acc.w += v * f[j].w;
        }
    }
    for (; i < num; ++i) {
        int2 r = erec[start + i];
        float4 f = xw4[r.x * 32 + l];
        float v = __int_as_float(r.y) * dinv[r.x];
        acc.x += v * f.x; acc.y += v * f.y; acc.z += v * f.z; acc.w += v * f.w;
    }
    float4 bb = bias4[l];
    acc.x = fmaxf(d * acc.x + bb.x, 0.0f);
    acc.y = fmaxf(d * acc.y + bb.y, 0.0f);
    acc.z = fmaxf(d * acc.z + bb.z, 0.0f);
    acc.w = fmaxf(d * acc.w + bb.w, 0.0f);
    out4[n * 32 + l] = acc;
}

// ---------------------------------------------------------------------------
// Fused temporal conv + fc: one wave per node, lane handles ch l and l+64.
__global__ __launch_bounds__(256) void convfc_kernel(const float* __restrict__ h,
        const float* __restrict__ v, const float* __restrict__ c0,
        float* __restrict__ out, int N) {
    int n = blockIdx.x * 4 + (threadIdx.x >> 6);
    int l = threadIdx.x & 63;
    if (n >= N) return;
    const float* hn = h + n * CH;
    float v0a = v[l * 3 + 0],        v1a = v[l * 3 + 1],        v2a = v[l * 3 + 2];
    float v0b = v[(l + 64) * 3 + 0], v1b = v[(l + 64) * 3 + 1], v2b = v[(l + 64) * 3 + 2];
    float p = hn[l] * v1a + hn[l + 64] * v1b;
    if (n > 0)     p += hn[l - CH] * v0a + hn[l + 64 - CH] * v0b;
    if (n < N - 1) p += hn[l + CH] * v2a + hn[l + 64 + CH] * v2b;
    #pragma unroll
    for (int off = 32; off > 0; off >>= 1) p += __shfl_down(p, off, 64);
    if (l == 0) out[n] = p + *c0;
}

// ---------------------------------------------------------------------------
extern "C" void kernel_launch(void* const* d_in, const int* in_sizes, int n_in,
                              void* d_out, int out_size, void* d_ws, size_t ws_size,
                              hipStream_t stream) {
    const float* x       = (const float*)d_in[0];
    const int*   ei      = (const int*)d_in[1];
    const float* ew      = (const float*)d_in[2];
    const float* W1      = (const float*)d_in[3];
    const float* b1      = (const float*)d_in[4];
    const float* W2      = (const float*)d_in[5];
    const float* b2      = (const float*)d_in[6];
    const float* conv_w  = (const float*)d_in[7];
    const float* conv_b  = (const float*)d_in[8];
    const float* fc_w    = (const float*)d_in[9];
    const float* fc_b    = (const float*)d_in[10];
    float* out = (float*)d_out;

    float* bufA   = (float*)d_ws;                   // 1,280,000 f
    float* bufB   = bufA + N_NODES * CH;            // 1,280,000 f
    int2*  erec   = (int2*)(bufB + N_NODES * CH);   // 640,000 x 8B
    int*   hist   = (int*)(erec + N_EDGES);         // NB*10,000 i
    int*   pcs    = hist + NB * N_NODES;            // NCHUNK*NB i
    int*   tot    = pcs + NCHUNK * NB;              // 10,000 i
    int*   offs   = tot + N_NODES;                  // 10,000 i
    float* dinv   = (float*)(offs + N_NODES);       // 10,000 f
    float* vbuf   = dinv + N_NODES;                 // 384 f
    float* c0     = vbuf + 384;                     // 1 f

    const int gemm_grid = (N_NODES + 63) / 64;      // 157

    // K1: hist (64) + gemm1 (157) + weight-fold (1), all data-independent
    fused_hist_gemm<<<NB + gemm_grid + 1, 256, 0, stream>>>(ei, x, W1, hist, pcs,
            bufA, conv_w, conv_b, fc_w, fc_b, vbuf, c0);
    bofs_kernel<<<NCHUNK, 256, 0, stream>>>(hist, pcs, tot, offs);
    scatter_kernel<<<NB, 256, 0, stream>>>(ei, ew, hist, erec);
    deg_kernel<<<N_NODES / 8, 256, 0, stream>>>(erec, offs, tot, dinv);

    // layer 1 aggregation (gemm1 output already in bufA)
    agg_kernel<<<N_NODES / 8, 256, 0, stream>>>((const float4*)bufA, erec, offs, tot,
                                                dinv, (const float4*)b1, (float4*)bufB);
    // layer 2
    gemm128_kernel<<<gemm_grid, 256, 0, stream>>>(bufB, W2, bufA, N_NODES);
    agg_kernel<<<N_NODES / 8, 256, 0, stream>>>((const float4*)bufA, erec, offs, tot,
                                                dinv, (const float4*)b2, (float4*)bufB);
    // fused temporal conv + fc
    convfc_kernel<<<(N_NODES + 3) / 4, 256, 0, stream>>>(bufB, vbuf, c0, out, N_NODES);
}

// Round 4
// 207.261 us; speedup vs baseline: 1.4619x; 1.0593x over previous
//
#include <hip/hip_runtime.h>
#include <hip/hip_bf16.h>

#define N_NODES 10000
#define N_EDGES 640000
#define CH 128
#define NB 64                // histogram/scatter blocks
#define EPB (N_EDGES / NB)   // 10000 edges per block
#define NCHUNK 40            // ceil(N_NODES/256) scan chunks
#define NPAD 10240           // NCHUNK*256

// ---------------------------------------------------------------------------
// K1: FUSED. Blocks [0,NB): per-block LDS DUAL histogram (count + weighted
// degree, 80 KB) + chunk count-partials. Blocks [NB, NB+157): gemm1 = x@W1^T.
// Block NB+157: conv/fc weight fold.
__global__ __launch_bounds__(256) void fused_hist_gemm(const int* __restrict__ ei,
        const float* __restrict__ ew,
        const float* __restrict__ x, const float* __restrict__ W1,
        int* __restrict__ hist, float* __restrict__ dhist, int* __restrict__ pcs,
        float* __restrict__ out,
        const float* __restrict__ conv_w, const float* __restrict__ conv_b,
        const float* __restrict__ fc_w, const float* __restrict__ fc_b,
        float* __restrict__ vbuf, float* __restrict__ c0) {
    __shared__ __align__(16) char smem[NPAD * 8];    // 80 KB union
    int t = threadIdx.x;
    int bid = blockIdx.x;
    if (bid < NB) {
        // ---- dual histogram path ----
        int* h = (int*)smem;                         // 40 KB counts
        float* hf = (float*)(smem + NPAD * 4);       // 40 KB weighted degree
        for (int i = t; i < 2 * NPAD; i += 256) ((int*)smem)[i] = 0;
        __syncthreads();
        int e0 = bid * EPB;
        for (int i = t; i < EPB; i += 256) {
            int e = e0 + i;
            int c = ei[N_EDGES + e];
            atomicAdd(&h[c], 1);                     // LDS atomics
            atomicAdd(&hf[c], ew[e]);
        }
        __syncthreads();
        for (int i = t; i < N_NODES; i += 256) {
            hist[bid * N_NODES + i] = h[i];
            dhist[bid * N_NODES + i] = hf[i];
        }
        // chunk count partials: wave w handles chunks w, w+4, ...
        int lane = t & 63, wave = t >> 6;
        for (int cch = wave; cch < NCHUNK; cch += 4) {
            int s = h[cch * 256 + lane] + h[cch * 256 + lane + 64]
                  + h[cch * 256 + lane + 128] + h[cch * 256 + lane + 192];
            #pragma unroll
            for (int off = 32; off > 0; off >>= 1) s += __shfl_down(s, off, 64);
            if (lane == 0) pcs[cch * NB + bid] = s;  // chunk-major layout
        }
        return;
    }
    if (bid == NB + (N_NODES + 63) / 64) {
        // ---- conv/fc weight folding ----
        for (int i = t; i <= 384; i += 256) {
            if (i < 384) {
                float s = 0.0f;
                for (int o = 0; o < CH; ++o) s += fc_w[o] * conv_w[o * 384 + i];
                vbuf[i] = s;
            } else {
                float s = fc_b[0];
                for (int o = 0; o < CH; ++o) s += fc_w[o] * conv_b[o];
                *c0 = s;
            }
        }
        return;
    }
    // ---- gemm path: out[m][o] = sum_k x[m][k] * W1[o][k] ----
    float (*As)[68]  = (float(*)[68])smem;
    float (*Ws)[132] = (float(*)[132])(smem + 32 * 68 * sizeof(float));
    int tx = t & 31;
    int ty = t >> 5;
    int row0 = (bid - NB) * 64;
    float acc[8][4] = {};
    for (int k0 = 0; k0 < 128; k0 += 32) {
        #pragma unroll
        for (int i = 0; i < 8; ++i) {
            int idx = t + i * 256;
            int r = idx >> 5, k = idx & 31;
            int gr = row0 + r;
            As[k][r] = (gr < N_NODES) ? x[gr * CH + k0 + k] : 0.0f;
        }
        #pragma unroll
        for (int i = 0; i < 16; ++i) {
            int idx = t + i * 256;
            int o = idx >> 5, k = idx & 31;
            Ws[k][o] = W1[o * CH + k0 + k];
        }
        __syncthreads();
        #pragma unroll
        for (int kk = 0; kk < 32; ++kk) {
            float a[8], w[4];
            #pragma unroll
            for (int j = 0; j < 8; ++j) a[j] = As[kk][ty * 8 + j];
            #pragma unroll
            for (int c = 0; c < 4; ++c) w[c] = Ws[kk][tx * 4 + c];
            #pragma unroll
            for (int j = 0; j < 8; ++j)
                #pragma unroll
                for (int c = 0; c < 4; ++c)
                    acc[j][c] += a[j] * w[c];
        }
        __syncthreads();
    }
    #pragma unroll
    for (int j = 0; j < 8; ++j) {
        int gr = row0 + ty * 8 + j;
        if (gr < N_NODES) {
            float4 v = make_float4(acc[j][0], acc[j][1], acc[j][2], acc[j][3]);
            *reinterpret_cast<float4*>(&out[gr * CH + tx * 4]) = v;
        }
    }
}

// ---------------------------------------------------------------------------
// K2: per-node totals + dinv + global exclusive prefix + cursor conversion.
__global__ __launch_bounds__(256) void bofs_kernel(int* __restrict__ hist,
        const float* __restrict__ dhist, const int* __restrict__ pcs,
        int* __restrict__ tot, int* __restrict__ offs, float* __restrict__ dinv) {
    __shared__ int wred[4];
    __shared__ int wsum[4];
    __shared__ int base_sh;
    int blk = blockIdx.x, t = threadIdx.x;
    int lane = t & 63, wave = t >> 6;
    // --- base = edges into nodes of earlier chunks ---
    int bsum = 0;
    for (int i = t; i < blk * NB; i += 256) bsum += pcs[i];
    #pragma unroll
    for (int off = 32; off > 0; off >>= 1) bsum += __shfl_down(bsum, off, 64);
    if (lane == 0) wred[wave] = bsum;
    __syncthreads();
    if (t == 0) base_sh = wred[0] + wred[1] + wred[2] + wred[3];
    // --- per-node totals (count + weighted degree) over 64 hist rows ---
    int n = blk * 256 + t;
    int v = 0;
    if (n < N_NODES) {
        float dsum = 0.0f;
        #pragma unroll 8
        for (int b = 0; b < NB; ++b) {
            v += hist[b * N_NODES + n];
            dsum += dhist[b * N_NODES + n];
        }
        tot[n] = v;
        dinv[n] = rsqrtf(dsum + 1.0f);            // +1 = self-loop weight
    }
    // --- 256-wide scan (wave scan + wave offsets) ---
    int s = v;
    #pragma unroll
    for (int off = 1; off < 64; off <<= 1) {
        int u = __shfl_up(s, off, 64);
        if (lane >= off) s += u;
    }
    if (lane == 63) wsum[wave] = s;
    __syncthreads();
    int wbase = 0;
    for (int i = 0; i < wave; ++i) wbase += wsum[i];
    if (n < N_NODES) {
        int run = base_sh + wbase + s - v;        // global exclusive prefix
        offs[n] = run;
        for (int b = 0; b < NB; ++b) {
            int h = hist[b * N_NODES + n];
            hist[b * N_NODES + n] = run;          // column -> start cursor
            run += h;
        }
    }
}

// ---------------------------------------------------------------------------
// K3: scatter edges into CSR order via LDS cursors; records carry the fully
// NORMALIZED value dinv[r]*w*dinv[c] (dinv staged in LDS).
__global__ __launch_bounds__(256) void scatter_kernel(const int* __restrict__ ei,
        const float* __restrict__ ew, const float* __restrict__ dinv,
        const int* __restrict__ bofs, int2* __restrict__ erec) {
    __shared__ int cur[N_NODES];                 // 40 KB
    __shared__ float di[N_NODES];                // 40 KB
    int b = blockIdx.x, t = threadIdx.x;
    for (int i = t; i < N_NODES; i += 256) {
        cur[i] = bofs[b * N_NODES + i];
        di[i] = dinv[i];
    }
    __syncthreads();
    int e0 = b * EPB;
    for (int i = t; i < EPB; i += 256) {
        int e = e0 + i;
        int r = ei[e];
        int c = ei[N_EDGES + e];
        float v = di[r] * ew[e] * di[c];
        int p = atomicAdd(&cur[c], 1);           // LDS atomic
        erec[p] = make_int2(r, __float_as_int(v));
    }
}

// ---------------------------------------------------------------------------
// K4: FUSED agg1 + gemm2. Each block aggregates 8 nodes (32 lanes/node),
// applies bias+relu, stages the 8 h1-rows in 4 KB LDS, then computes
// out[n] = h1[n] @ W2^T directly (h1 never hits global memory).
__global__ __launch_bounds__(256) void agg_gemm_kernel(const float4* __restrict__ xw4,
        const int2* __restrict__ erec, const int* __restrict__ offs,
        const int* __restrict__ cnt, const float* __restrict__ dinv,
        const float4* __restrict__ bias4, const float* __restrict__ W2,
        float* __restrict__ out) {
    __shared__ float hs[8][128];                 // 4 KB relu'd h1 rows
    int l = threadIdx.x & 31;                    // channel quad
    int g = threadIdx.x >> 5;                    // node group 0..7
    int n = blockIdx.x * 8 + g;
    float d = dinv[n];
    float dd = d * d;
    float4 self = xw4[n * 32 + l];
    float4 acc = make_float4(dd * self.x, dd * self.y, dd * self.z, dd * self.w);
    int start = offs[n];
    int num = cnt[n];
    int i = 0;
    for (; i + 8 <= num; i += 8) {
        int2 r[8];
        #pragma unroll
        for (int j = 0; j < 8; ++j) r[j] = erec[start + i + j];
        float4 f[8];
        #pragma unroll
        for (int j = 0; j < 8; ++j) f[j] = xw4[r[j].x * 32 + l];
        #pragma unroll
        for (int j = 0; j < 8; ++j) {
            float v = __int_as_float(r[j].y);
            acc.x += v * f[j].x; acc.y += v * f[j].y;
            acc.z += v * f[j].z; acc.w += v * f[j].w;
        }
    }
    for (; i < num; ++i) {
        int2 r = erec[start + i];
        float4 f = xw4[r.x * 32 + l];
        float v = __int_as_float(r.y);
        acc.x += v * f.x; acc.y += v * f.y; acc.z += v * f.z; acc.w += v * f.w;
    }
    float4 bb = bias4[l];
    acc.x = fmaxf(acc.x + bb.x, 0.0f);
    acc.y = fmaxf(acc.y + bb.y, 0.0f);
    acc.z = fmaxf(acc.z + bb.z, 0.0f);
    acc.w = fmaxf(acc.w + bb.w, 0.0f);
    *reinterpret_cast<float4*>(&hs[g][4 * l]) = acc;
    __syncthreads();
    // ---- mini-GEMM: thread = (output channel o, row-group rg of 4 rows) ----
    int o = threadIdx.x & 127;
    int rg = threadIdx.x >> 7;                   // 0: rows 0-3, 1: rows 4-7
    const float4* w4p = reinterpret_cast<const float4*>(&W2[o * CH]);
    const float4* h0p = reinterpret_cast<const float4*>(&hs[rg * 4 + 0][0]);
    const float4* h1p = reinterpret_cast<const float4*>(&hs[rg * 4 + 1][0]);
    const float4* h2p = reinterpret_cast<const float4*>(&hs[rg * 4 + 2][0]);
    const float4* h3p = reinterpret_cast<const float4*>(&hs[rg * 4 + 3][0]);
    float a0 = 0.0f, a1 = 0.0f, a2 = 0.0f, a3 = 0.0f;
    #pragma unroll 8
    for (int k4 = 0; k4 < 32; ++k4) {
        float4 w = w4p[k4];                      // L2-hot W2 row
        float4 h0 = h0p[k4], h1 = h1p[k4], h2 = h2p[k4], h3 = h3p[k4];
        a0 += w.x * h0.x + w.y * h0.y + w.z * h0.z + w.w * h0.w;
        a1 += w.x * h1.x + w.y * h1.y + w.z * h1.z + w.w * h1.w;
        a2 += w.x * h2.x + w.y * h2.y + w.z * h2.z + w.w * h2.w;
        a3 += w.x * h3.x + w.y * h3.y + w.z * h3.z + w.w * h3.w;
    }
    int nb = blockIdx.x * 8 + rg * 4;
    out[(nb + 0) * CH + o] = a0;
    out[(nb + 1) * CH + o] = a1;
    out[(nb + 2) * CH + o] = a2;
    out[(nb + 3) * CH + o] = a3;
}

// ---------------------------------------------------------------------------
// K5: aggregation layer 2 (normalized records): out = relu(dd*self + sum + b).
__global__ __launch_bounds__(256) void agg_kernel(const float4* __restrict__ xw4,
        const int2* __restrict__ erec, const int* __restrict__ offs,
        const int* __restrict__ cnt, const float* __restrict__ dinv,
        const float4* __restrict__ bias4, float4* __restrict__ out4) {
    int l = threadIdx.x & 31;
    int g = threadIdx.x >> 5;
    int n = blockIdx.x * 8 + g;
    float d = dinv[n];
    float dd = d * d;
    float4 self = xw4[n * 32 + l];
    float4 acc = make_float4(dd * self.x, dd * self.y, dd * self.z, dd * self.w);
    int start = offs[n];
    int num = cnt[n];
    int i = 0;
    for (; i + 8 <= num; i += 8) {
        int2 r[8];
        #pragma unroll
        for (int j = 0; j < 8; ++j) r[j] = erec[start + i + j];
        float4 f[8];
        #pragma unroll
        for (int j = 0; j < 8; ++j) f[j] = xw4[r[j].x * 32 + l];
        #pragma unroll
        for (int j = 0; j < 8; ++j) {
            float v = __int_as_float(r[j].y);
            acc.x += v * f[j].x; acc.y += v * f[j].y;
            acc.z += v * f[j].z; acc.w += v * f[j].w;
        }
    }
    for (; i < num; ++i) {
        int2 r = erec[start + i];
        float4 f = xw4[r.x * 32 + l];
        float v = __int_as_float(r.y);
        acc.x += v * f.x; acc.y += v * f.y; acc.z += v * f.z; acc.w += v * f.w;
    }
    float4 bb = bias4[l];
    acc.x = fmaxf(acc.x + bb.x, 0.0f);
    acc.y = fmaxf(acc.y + bb.y, 0.0f);
    acc.z = fmaxf(acc.z + bb.z, 0.0f);
    acc.w = fmaxf(acc.w + bb.w, 0.0f);
    out4[n * 32 + l] = acc;
}

// ---------------------------------------------------------------------------
// K6: fused temporal conv + fc: one wave per node, lane handles ch l and l+64.
__global__ __launch_bounds__(256) void convfc_kernel(const float* __restrict__ h,
        const float* __restrict__ v, const float* __restrict__ c0,
        float* __restrict__ out, int N) {
    int n = blockIdx.x * 4 + (threadIdx.x >> 6);
    int l = threadIdx.x & 63;
    if (n >= N) return;
    const float* hn = h + n * CH;
    float v0a = v[l * 3 + 0],        v1a = v[l * 3 + 1],        v2a = v[l * 3 + 2];
    float v0b = v[(l + 64) * 3 + 0], v1b = v[(l + 64) * 3 + 1], v2b = v[(l + 64) * 3 + 2];
    float p = hn[l] * v1a + hn[l + 64] * v1b;
    if (n > 0)     p += hn[l - CH] * v0a + hn[l + 64 - CH] * v0b;
    if (n < N - 1) p += hn[l + CH] * v2a + hn[l + 64 + CH] * v2b;
    #pragma unroll
    for (int off = 32; off > 0; off >>= 1) p += __shfl_down(p, off, 64);
    if (l == 0) out[n] = p + *c0;
}

// ---------------------------------------------------------------------------
extern "C" void kernel_launch(void* const* d_in, const int* in_sizes, int n_in,
                              void* d_out, int out_size, void* d_ws, size_t ws_size,
                              hipStream_t stream) {
    const float* x       = (const float*)d_in[0];
    const int*   ei      = (const int*)d_in[1];
    const float* ew      = (const float*)d_in[2];
    const float* W1      = (const float*)d_in[3];
    const float* b1      = (const float*)d_in[4];
    const float* W2      = (const float*)d_in[5];
    const float* b2      = (const float*)d_in[6];
    const float* conv_w  = (const float*)d_in[7];
    const float* conv_b  = (const float*)d_in[8];
    const float* fc_w    = (const float*)d_in[9];
    const float* fc_b    = (const float*)d_in[10];
    float* out = (float*)d_out;

    float* bufA   = (float*)d_ws;                   // 1,280,000 f (xw1, later h2)
    float* bufB   = bufA + N_NODES * CH;            // 1,280,000 f (xw2)
    int2*  erec   = (int2*)(bufB + N_NODES * CH);   // 640,000 x 8B
    int*   hist   = (int*)(erec + N_EDGES);         // NB*10,000 i
    float* dhist  = (float*)(hist + NB * N_NODES);  // NB*10,000 f
    int*   pcs    = (int*)(dhist + NB * N_NODES);   // NCHUNK*NB i
    int*   tot    = pcs + NCHUNK * NB;              // 10,000 i
    int*   offs   = tot + N_NODES;                  // 10,000 i
    float* dinv   = (float*)(offs + N_NODES);       // 10,000 f
    float* vbuf   = dinv + N_NODES;                 // 384 f
    float* c0     = vbuf + 384;                     // 1 f

    const int gemm_grid = (N_NODES + 63) / 64;      // 157

    // K1: dual-hist (64) + gemm1 (157) + weight-fold (1), all data-independent
    fused_hist_gemm<<<NB + gemm_grid + 1, 256, 0, stream>>>(ei, ew, x, W1,
            hist, dhist, pcs, bufA, conv_w, conv_b, fc_w, fc_b, vbuf, c0);
    // K2: totals + dinv + prefix + cursor conversion
    bofs_kernel<<<NCHUNK, 256, 0, stream>>>(hist, dhist, pcs, tot, offs, dinv);
    // K3: normalized CSR scatter
    scatter_kernel<<<NB, 256, 0, stream>>>(ei, ew, dinv, hist, erec);
    // K4: agg layer 1 + gemm2 fused (h1 never materialized): bufA -> bufB
    agg_gemm_kernel<<<N_NODES / 8, 256, 0, stream>>>((const float4*)bufA, erec, offs,
            tot, dinv, (const float4*)b1, W2, bufB);
    // K5: agg layer 2: bufB -> bufA
    agg_kernel<<<N_NODES / 8, 256, 0, stream>>>((const float4*)bufB, erec, offs, tot,
                                                dinv, (const float4*)b2, (float4*)bufA);
    // K6: fused temporal conv + fc
    convfc_kernel<<<(N_NODES + 3) / 4, 256, 0, stream>>>(bufA, vbuf, c0, out, N_NODES);
}